// Round 4
// baseline (867.355 us; speedup 1.0000x reference)
//
#include <hip/hip_runtime.h>
#include <math.h>

#define NIMG 8
#define NCLS 80
#define HW 40000
#define M (NCLS*HW)          // 3,200,000 per image
#define NBINS 2048
#define BIN_SHIFT 20         // top 12 bits of positive float (16 bins/octave)
#define CAND_MAX 4096
#define SPILL_CAP 65536
#define CAP2 8192
#define SPILL_BIN 1000       // bin of 0.25f (0x3E800000 >> 20)
#define TOPK 1000
#define OUTK 100
#define PRE_T 0.05f
#define PRE_T_LOOSE 0.0499f
#define NMS_T 0.6f
#define L2E 1.44269504f

#define CG 4                 // class groups
#define CPG (NCLS/CG)        // 20 classes per group
#define HWC 2048             // hw positions per block
#define NHWB ((HW + HWC - 1)/HWC)   // 20

// device-global scratch (no ws dependence). g_part fully overwritten each call;
// counters zeroed by k0; everything else guarded by fresh counts/flags.
__device__ unsigned int       g_part[NIMG][CG*NHWB][NBINS];   // 5.2 MB
__device__ unsigned int       g_hist[NIMG][NBINS];
__device__ unsigned int       g_scnt[NIMG];
__device__ unsigned int       g_cnt2[NIMG];
__device__ int                g_ccut[NIMG], g_rcut[NIMG], g_flag[NIMG];
__device__ unsigned long long g_spill[NIMG][SPILL_CAP];       // 4.2 MB
__device__ unsigned long long g_spill2[NIMG][CAP2];
__device__ unsigned long long g_top[NIMG][1024];

__device__ __forceinline__ float sigmoid_fast(float x){
    // approx (v_exp+v_rcp, ~1e-6 rel) — screening/binning only; 1 bin = 6% wide
    return __builtin_amdgcn_rcpf(1.0f + __builtin_amdgcn_exp2f(-x * L2E));
}
__device__ __forceinline__ float sigmoid_exact(float x){
    return 1.0f / (1.0f + expf(-x));   // bit-matches ref (R1-R3: absmax 0)
}

__global__ void k0_zero(){
    int t = threadIdx.x;
    if (t < NIMG){ g_scnt[t] = 0u; g_cnt2[t] = 0u; }
}

// Single streaming pass: hist(approx bins) + spill(approx>=0.25 candidates).
// hw-major: ct in registers once; class loop ping-pongs cls loads, pinned by
// sched_barrier so the next load issues before the branchy compute.
__global__ void __launch_bounds__(512) k1_fused(const float* __restrict__ cls,
                                                const float* __restrict__ cent){
    const int n   = blockIdx.z;
    const int cg  = blockIdx.y;
    const int bx  = blockIdx.x;
    const int tid = threadIdx.x;
    const int hw0 = bx * HWC;
    const int c0  = cg * CPG;
    __shared__ unsigned int sh[NBINS];
    for (int i = tid; i < NBINS; i += 512) sh[i] = 0u;
    const float* cls_n  = cls  + (size_t)n * M;
    const float* cent_n = cent + (size_t)n * HW;
    const int  hwt = hw0 + tid * 4;
    const bool act = hwt < HW;               // HW%4==0: act => full float4 valid
    const float* cptr = cent_n + (act ? hwt : 0);
    float4 cv = *(const float4*)cptr;
    float cta[4] = { sigmoid_fast(cv.x), sigmoid_fast(cv.y),
                     sigmoid_fast(cv.z), sigmoid_fast(cv.w) };
    __syncthreads();
    const float* base = cls_n + (act ? hwt : 0);
    float4 xc = *(const float4*)(base + (size_t)c0 * HW);
    for (int cc = 0; cc < CPG; ++cc){
        const int c = c0 + cc;
        float4 xn = xc;
        if (cc + 1 < CPG) xn = *(const float4*)(base + (size_t)(c+1) * HW);
        __builtin_amdgcn_sched_barrier(0);   // pin: next load issues before compute
        if (act){
            float xs[4] = {xc.x, xc.y, xc.z, xc.w};
            #pragma unroll
            for (int j = 0; j < 4; ++j){
                float pa = sigmoid_fast(xs[j]);
                if (pa > PRE_T_LOOSE){
                    unsigned int bits = __float_as_uint(pa * cta[j]);
                    unsigned int bin = bits >> BIN_SHIFT;
                    atomicAdd(&sh[bin], 1u);
                    if (bin >= SPILL_BIN){
                        unsigned int pos = atomicAdd(&g_scnt[n], 1u);
                        if (pos < SPILL_CAP){
                            unsigned int idx = (unsigned int)((hwt + j) * NCLS + c);
                            g_spill[n][pos] = ((unsigned long long)bits << 32) | idx;
                        }
                    }
                }
            }
        }
        __builtin_amdgcn_sched_barrier(0);   // pin: compute done before reg swap
        xc = xn;
    }
    __syncthreads();
    unsigned int* dst = g_part[n][cg * NHWB + bx];
    for (int i = tid; i < NBINS; i += 512) dst[i] = sh[i];
}

// Stage-A reduction: parallel sum of 80 partial hists (don't serialize on 1 CU)
__global__ void k2a_reduce(){
    int n = blockIdx.y;
    int bin = blockIdx.x * 256 + threadIdx.x;
    unsigned int s = 0;
    #pragma unroll 8
    for (int p = 0; p < CG*NHWB; ++p) s += g_part[n][p][bin];
    g_hist[n][bin] = s;
}

// Stage-B: rawcut (suffix>=TOPK), ccut=rawcut-2 (clamped), rcut=rawcut-1,
// fallback flag if spill floor above ccut or spill overflowed.
__global__ void k2b_cut(){
    int n = blockIdx.x;
    __shared__ unsigned int hist[NBINS];
    __shared__ unsigned int csum[256];
    for (int b = threadIdx.x; b < NBINS; b += 256) hist[b] = g_hist[n][b];
    __syncthreads();
    {
        unsigned int s = 0;
        int base = threadIdx.x * 8;
        #pragma unroll
        for (int i = 0; i < 8; ++i) s += hist[base + i];
        csum[threadIdx.x] = s;
    }
    __syncthreads();
    if (threadIdx.x == 0){
        unsigned int acc = 0; int rawcut = 0; int c = 255;
        for (; c >= 0; --c){ if (acc + csum[c] >= TOPK) break; acc += csum[c]; }
        if (c >= 0){
            int b = c*8 + 7;
            for (;; --b){ acc += hist[b]; if (acc >= TOPK || b == c*8) break; }
            rawcut = b;
        }
        int ccut = rawcut; unsigned int cnt = acc;
        for (int m = 0; m < 2 && ccut > 0; ++m){ ccut--; cnt += hist[ccut]; }
        while (cnt > CAND_MAX && ccut < NBINS){ cnt -= hist[ccut]; ccut++; }
        int rcut = rawcut > 0 ? rawcut - 1 : 0;
        if (rcut < ccut) rcut = ccut;
        g_ccut[n] = ccut; g_rcut[n] = rcut;
        g_flag[n] = (g_scnt[n] > SPILL_CAP) || (SPILL_BIN > ccut) ? 1 : 0;
    }
}

// Fallback full rescan (normally a ~3us no-op): guarantees correctness if the
// static spill floor was above the data-dependent cut, or spill overflowed.
__global__ void k3_fallback(const float* __restrict__ cls,
                            const float* __restrict__ cent){
    int n = blockIdx.y;
    if (!g_flag[n]) return;
    unsigned int ccut = (unsigned int)g_ccut[n];
    const float* cls_n  = cls  + (size_t)n * M;
    const float* cent_n = cent + (size_t)n * HW;
    const int chunk = M / 64;     // 50000
    int beg = blockIdx.x * chunk;
    for (int t = beg + threadIdx.x; t < beg + chunk; t += 256){
        float pa = sigmoid_fast(cls_n[t]);
        if (pa > PRE_T_LOOSE){
            int hw = t % HW;
            unsigned int bits = __float_as_uint(pa * sigmoid_fast(cent_n[hw]));
            if ((bits >> BIN_SHIFT) >= ccut){
                unsigned int pos = atomicAdd(&g_cnt2[n], 1u);
                if (pos < CAP2){
                    int c = t / HW;
                    unsigned int idx = (unsigned int)(hw * NCLS + c);
                    g_spill2[n][pos] = ((unsigned long long)bits << 32) | idx;
                }
            }
        }
    }
}

// Filter spill by approx bin>=ccut, re-score survivors EXACTLY (expf), filter
// exact bin>=rcut, exact rank-select top-1000 (unique composite keys).
__global__ void __launch_bounds__(1024) k4_select(const float* __restrict__ cls,
                                                  const float* __restrict__ cent){
    int n = blockIdx.x;
    __shared__ unsigned long long keys[CAND_MAX];
    __shared__ unsigned int lcnt;
    if (threadIdx.x == 0) lcnt = 0;
    g_top[n][threadIdx.x] = 0ull;
    __syncthreads();
    int fb = g_flag[n];
    const unsigned long long* src = fb ? g_spill2[n] : g_spill[n];
    unsigned int cap = fb ? CAP2 : SPILL_CAP;
    unsigned int S = fb ? g_cnt2[n] : g_scnt[n];
    if (S > cap) S = cap;
    unsigned int ccut = (unsigned int)g_ccut[n];
    unsigned int rcut = (unsigned int)g_rcut[n];
    const float* cls_n  = cls  + (size_t)n * M;
    const float* cent_n = cent + (size_t)n * HW;
    for (unsigned int i = threadIdx.x; i < S; i += 1024){
        unsigned long long e = src[i];
        unsigned int abin = (unsigned int)(e >> (32 + BIN_SHIFT));
        if (abin >= ccut){
            unsigned int idx = (unsigned int)e;
            unsigned int c  = idx % NCLS;
            unsigned int hw = idx / NCLS;
            float p = sigmoid_exact(cls_n[(size_t)c*HW + hw]);
            if (p > PRE_T){
                float s = p * sigmoid_exact(cent_n[hw]);
                unsigned int bits = __float_as_uint(s);
                if ((bits >> BIN_SHIFT) >= rcut){
                    unsigned int pos = atomicAdd(&lcnt, 1u);
                    if (pos < CAND_MAX)
                        keys[pos] = ((unsigned long long)bits << 32)
                                  | (unsigned long long)(0xFFFFFFFFu - idx);
                }
            }
        }
    }
    __syncthreads();
    int C = (int)(lcnt < CAND_MAX ? lcnt : CAND_MAX);
    for (int i = threadIdx.x; i < C; i += 1024){
        unsigned long long k = keys[i];
        int rank = 0;
        for (int j = 0; j < C; ++j) rank += (keys[j] > k) ? 1 : 0;
        if (rank < TOPK) g_top[n][rank] = k;
    }
}

// Decode boxes, greedy NMS with early stop at 100 keeps, write output
__global__ void __launch_bounds__(1024) k5_nms(const float* __restrict__ loc,
                                               const float* __restrict__ reg,
                                               const int*   __restrict__ imsz,
                                               float* __restrict__ out){
    int n = blockIdx.x;
    int t = threadIdx.x;
    __shared__ float ox1[TOPK], oy1[TOPK], ox2[TOPK], oy2[TOPK], oar[TOPK];
    __shared__ float bx[TOPK][4];
    __shared__ float sc[TOPK];
    __shared__ int   lab[TOPK];
    __shared__ unsigned char validf[TOPK];
    __shared__ unsigned char supp[TOPK];
    __shared__ int keeplist[OUTK];

    if (t < TOPK){
        unsigned long long k = g_top[n][t];
        unsigned int bits = (unsigned int)(k >> 32);
        float s = __uint_as_float(bits);
        supp[t] = 0;
        if (s > 0.0f){
            unsigned int idx = 0xFFFFFFFFu - (unsigned int)(k & 0xFFFFFFFFull);
            int hw = (int)(idx / NCLS);
            int c  = (int)(idx % NCLS);
            int l  = c + 1;
            float x  = loc[2*hw], y = loc[2*hw + 1];
            float r0 = reg[((size_t)n*4 + 0)*HW + hw];
            float r1 = reg[((size_t)n*4 + 1)*HW + hw];
            float r2 = reg[((size_t)n*4 + 2)*HW + hw];
            float r3 = reg[((size_t)n*4 + 3)*HW + hw];
            float ihh = (float)imsz[2*n + 0];
            float iww = (float)imsz[2*n + 1];
            float x1 = fminf(fmaxf(x - r0, 0.0f), iww - 1.0f);
            float y1 = fminf(fmaxf(y - r1, 0.0f), ihh - 1.0f);
            float x2 = fminf(fmaxf(x + r2, 0.0f), iww - 1.0f);
            float y2 = fminf(fmaxf(y + r3, 0.0f), ihh - 1.0f);
            bx[t][0] = x1; bx[t][1] = y1; bx[t][2] = x2; bx[t][3] = y2;
            float off = (float)l * 100000.0f;   // fp32, as reference (quantizes!)
            float a1 = x1 + off, b1 = y1 + off, a2 = x2 + off, b2 = y2 + off;
            ox1[t] = a1; oy1[t] = b1; ox2[t] = a2; oy2[t] = b2;
            oar[t] = (a2 - a1 + 1.0f) * (b2 - b1 + 1.0f);
            sc[t] = s; lab[t] = l; validf[t] = 1;
        } else {
            validf[t] = 0; sc[t] = 0.0f; lab[t] = 0;
            bx[t][0] = bx[t][1] = bx[t][2] = bx[t][3] = 0.0f;
            ox1[t] = oy1[t] = 0.0f; ox2[t] = oy2[t] = -1.0f; oar[t] = 1.0f;
        }
    }
    __syncthreads();

    int cnt = 0;
    for (int i = 0; i < TOPK; ++i){
        bool keep_i = validf[i] && !supp[i];   // uniform LDS broadcast
        if (keep_i){
            if (t == 0) keeplist[cnt] = i;
            if (t < TOPK && t != i){
                float ix1 = fmaxf(ox1[i], ox1[t]);
                float iy1 = fmaxf(oy1[i], oy1[t]);
                float ix2 = fminf(ox2[i], ox2[t]);
                float iy2 = fminf(oy2[i], oy2[t]);
                float iw_ = fmaxf(ix2 - ix1 + 1.0f, 0.0f);
                float ih_ = fmaxf(iy2 - iy1 + 1.0f, 0.0f);
                float inter = iw_ * ih_;
                float iou = inter / (oar[i] + oar[t] - inter);
                if (iou > NMS_T) supp[t] = 1;
            }
            cnt++;
            __syncthreads();
            if (cnt == OUTK) break;    // keeps beyond 100 can't reach output
        }
    }
    __syncthreads();

    if (t < OUTK){
        float r0=0.f,r1=0.f,r2=0.f,r3=0.f,r4=0.f,r5=0.f;
        if (t < cnt){
            int i = keeplist[t];
            r0 = bx[i][0]; r1 = bx[i][1]; r2 = bx[i][2]; r3 = bx[i][3];
            r4 = sqrtf(sc[i]); r5 = (float)lab[i];
        }
        float* o = out + ((size_t)n*OUTK + t)*6;
        o[0]=r0; o[1]=r1; o[2]=r2; o[3]=r3; o[4]=r4; o[5]=r5;
    }
}

extern "C" void kernel_launch(void* const* d_in, const int* in_sizes, int n_in,
                              void* d_out, int out_size, void* d_ws, size_t ws_size,
                              hipStream_t stream){
    const float* loc  = (const float*)d_in[0];
    const float* cls  = (const float*)d_in[1];
    const float* reg  = (const float*)d_in[2];
    const float* cent = (const float*)d_in[3];
    const int*   imsz = (const int*)d_in[4];
    float* out = (float*)d_out;

    hipLaunchKernelGGL(k0_zero,     dim3(1),              dim3(64),   0, stream);
    hipLaunchKernelGGL(k1_fused,    dim3(NHWB, CG, NIMG), dim3(512),  0, stream, cls, cent);
    hipLaunchKernelGGL(k2a_reduce,  dim3(NBINS/256, NIMG),dim3(256),  0, stream);
    hipLaunchKernelGGL(k2b_cut,     dim3(NIMG),           dim3(256),  0, stream);
    hipLaunchKernelGGL(k3_fallback, dim3(64, NIMG),       dim3(256),  0, stream, cls, cent);
    hipLaunchKernelGGL(k4_select,   dim3(NIMG),           dim3(1024), 0, stream, cls, cent);
    hipLaunchKernelGGL(k5_nms,      dim3(NIMG),           dim3(1024), 0, stream,
                       loc, reg, imsz, out);
}